// Round 6
// baseline (300.100 us; speedup 1.0000x reference)
//
#include <hip/hip_runtime.h>

// SimVQuantizer: B=8, D=128 (N_CB=8 x CDIM=16), H=W=32 -> 8192 pixels.
// Outputs (FLOAT32, concatenated flat):
//   quantized  [8,128,32,32]  = 1048576   @ 0
//   indices    [8,8,32,32]    =   65536   @ 1048576
//   commitment scalar         =       1   @ 1114112
//   new_codebooks [8,1024,16] =  131072   @ 1114113
//   new_count  [8,1024]       =    8192   @ 1245185
//   new_weight [8,1024,16]    =  131072   @ 1253377

#define NCB   8
#define VOCAB 1024
#define CDIM  16
#define NPIX  8192   // B*H*W
#define HW    1024   // H*W

#define OFF_QUANT  0
#define OFF_IDX    1048576
#define OFF_COMMIT 1114112
#define OFF_NCB    1114113
#define OFF_NCNT   1245185
#define OFF_NWT    1253377

// workspace (floats): commit partials only — one per k_assign block.
// No memset needed: all 1024 words are written before k_statsupd reads them.
#define WS_CARR_OFF 0

// numpy pairwise_sum (order-preserving 8-accumulator) for n=16:
// r[j] = a[j] + a[j+8];  res = ((r0+r1)+(r2+r3)) + ((r4+r5)+(r6+r7))
__device__ __forceinline__ float npsum16(const float m[16]) {
#pragma clang fp contract(off)
  float r0 = m[0] + m[8];
  float r1 = m[1] + m[9];
  float r2 = m[2] + m[10];
  float r3 = m[3] + m[11];
  float r4 = m[4] + m[12];
  float r5 = m[5] + m[13];
  float r6 = m[6] + m[14];
  float r7 = m[7] + m[15];
  return ((r0 + r1) + (r2 + r3)) + ((r4 + r5) + (r6 + r7));
}

__device__ __forceinline__ float npsum16sq(const float a[16]) {
#pragma clang fp contract(off)
  float m[16];
#pragma unroll
  for (int d = 0; d < 16; ++d) m[d] = a[d] * a[d];
  return npsum16(m);
}

// One entry's distance + argmin step. numpy einsum (optimize=False) npyv
// contig order for n=16, then (z2 - 2*dot) + c2 — bit-identical to v1.
__device__ __forceinline__ void proc_entry(const float zv[16],
                                           const float e[16], float c2v,
                                           float z2, int idx, float& best,
                                           int& bi) {
#pragma clang fp contract(off)
  float m[16];
#pragma unroll
  for (int d = 0; d < 16; ++d) m[d] = zv[d] * e[d];
  float l0 = (m[0] + m[4]) + (m[8] + m[12]);
  float l1 = (m[1] + m[5]) + (m[9] + m[13]);
  float l2 = (m[2] + m[6]) + (m[10] + m[14]);
  float l3 = (m[3] + m[7]) + (m[11] + m[15]);
  const float dot = (l0 + l1) + (l2 + l3);
  const float d2 = (z2 - 2.0f * dot) + c2v;
  const bool lt = d2 < best;  // strict: ascending scan -> first-wins
  best = lt ? d2 : best;
  bi = lt ? idx : bi;
}

// v7: k_assign UNCHANGED from v6 (control: 63.6us, VALUBusy 64%).
// Entries stream via wave-uniform scalar loads; no atomics anywhere.
__global__ __launch_bounds__(512, 4) void k_assign(
    const float* __restrict__ z, const float* __restrict__ cb,
    float* __restrict__ out, float* __restrict__ ws_commit_arr) {
  __shared__ float s_c2[VOCAB];    // 4KB
  __shared__ float s_best[8 * 64]; // 2KB
  __shared__ int s_bi[8 * 64];     // 2KB

  const int c = blockIdx.x >> 7;
  const int pchunk = blockIdx.x & 127;
  const int t = threadIdx.x;
  const int pix = t & 63;
  const int w = t >> 6;
  // provably wave-uniform wave id -> scalar (SGPR) entry addressing below
  const int wu = __builtin_amdgcn_readfirstlane(w);

  const float* cbc = cb + (size_t)c * VOCAB * CDIM;

  // ||cb||^2 for all 1024 entries (np.sum(cb*cb,-1), pairwise 8-acc order)
  for (int v = t; v < VOCAB; v += 512) {
    float e[16];
#pragma unroll
    for (int d = 0; d < 16; ++d) e[d] = cbc[(size_t)v * CDIM + d];
    s_c2[v] = npsum16sq(e);
  }

  const int n = pchunk * 64 + pix;  // pixel id in [0, 8192)
  const int b = n >> 10;            // batch
  const int hw = n & 1023;          // h*W + w

  // zp[n,c,d] = z[b, c*16+d, h, w]; 64-lane coalesced per d
  const float* zbase = z + ((size_t)(b * 128 + c * 16)) * HW + hw;
  float zv[16];
#pragma unroll
  for (int d = 0; d < 16; ++d) zv[d] = zbase[(size_t)d * HW];

  const float z2 = npsum16sq(zv);

  __syncthreads();  // s_c2 ready

  // wave wu scans entries [wu*128, wu*128+128), ascending
  const int vbase = wu * 128;
  const float* ep = cbc + (size_t)vbase * CDIM;  // uniform (SGPR) pointer

  float best = INFINITY;
  int bi = 0;

#pragma unroll 2
  for (int k = 0; k < 128; k += 2) {
    // two entries per body; unroll 2 -> 4 entries of load-ahead slack for
    // the scheduler. All addresses uniform -> scalar loads.
    float ea[16], eb[16];
#pragma unroll
    for (int d = 0; d < 16; ++d) ea[d] = ep[(size_t)k * CDIM + d];
#pragma unroll
    for (int d = 0; d < 16; ++d) eb[d] = ep[(size_t)(k + 1) * CDIM + d];
    const float cv0 = s_c2[vbase + k];
    const float cv1 = s_c2[vbase + k + 1];
    proc_entry(zv, ea, cv0, z2, vbase + k, best, bi);
    proc_entry(zv, eb, cv1, z2, vbase + k + 1, best, bi);
  }

  s_best[w * 64 + pix] = best;
  s_bi[w * 64 + pix] = bi;
  __syncthreads();

  // wave 0: combine the 8 per-wave candidates. Wave slices are disjoint
  // ascending ranges; break float ties by lower index -> np.argmin
  // first-wins exactly.
  if (t < 64) {
    best = s_best[t];
    bi = s_bi[t];
#pragma unroll
    for (int s = 1; s < 8; ++s) {
      const float ob = s_best[s * 64 + t];
      const int oi = s_bi[s * 64 + t];
      const bool take = (ob < best) || (ob == best && oi < bi);
      best = take ? ob : best;
      bi = take ? oi : bi;
    }

    // t<64 => wave 0, pix == t: zv holds THIS pixel's z (bit-identical)
    const float* qe = cbc + (size_t)bi * CDIM;  // winning entry (L2-hot)
    float comm = 0.f;
#pragma unroll
    for (int d = 0; d < 16; ++d) {
      float zq = qe[d];
      float diff, qst;
      {
#pragma clang fp contract(off)
        diff = zv[d] - zq;
        qst = zv[d] + (zq - zv[d]);  // zq_st = zp + (zq - zp), as np computes
      }
      comm += diff * diff;
      out[OFF_QUANT + ((size_t)(b * 128 + c * 16 + d)) * HW + hw] = qst;
    }
    out[OFF_IDX + ((size_t)(b * NCB + c)) * HW + hw] = (float)bi;

    // commitment partial: reduce across wave 0's 64 lanes, ONE plain store
    // per block (no atomics anywhere in this kernel).
#pragma unroll
    for (int off = 32; off; off >>= 1) comm += __shfl_down(comm, off);
    if (t == 0) ws_commit_arr[blockIdx.x] = comm;
  }
}

// k_statsupd: fused stats + EMA update. 8 blocks (one per codebook c) x
// 1024 threads. Bin counts/sums for ALL of c in LDS (sums padded to
// stride 17: stride 16 would put all 64 lanes of each atomic wave-op on
// one bank = 32-way conflict), then write every c-output coalesced —
// no workspace round-trip, no extra kernel boundary, zero global atomics.
// idx loads all hoisted; z double-buffered across the 8 batches so the
// HBM/cross-XCD latency is exposed once, not 8 times (v6 k_stats lesson).
__global__ __launch_bounds__(1024) void k_statsupd(
    const float* __restrict__ z, const float* __restrict__ outbuf,
    const float* __restrict__ ema_count, const float* __restrict__ ema_weight,
    const float* __restrict__ ws_commit_arr, float* __restrict__ out) {
  __shared__ float s_sum[VOCAB * 17];  // 68KB, padded
  __shared__ float s_cnt[VOCAB];       // 4KB
  __shared__ float s_fred[16];
  __shared__ float s_n;
  __shared__ double s_dred[16];

  const int c = blockIdx.x;
  const int t = threadIdx.x;
  const int lane = t & 63;
  const int wv = t >> 6;

  // zero the histograms
#pragma unroll
  for (int j = 0; j < 17; ++j) s_sum[j * 1024 + t] = 0.f;
  s_cnt[t] = 0.f;
  __syncthreads();

  // hoist all 8 idx loads (independent; one latency exposure)
  int bidx[8];
#pragma unroll
  for (int k = 0; k < 8; ++k)
    bidx[k] = (int)outbuf[OFF_IDX + ((size_t)(k * NCB + c)) * HW + t];

  // z double-buffer: loads for batch k+1 in flight during batch k's atomics
  float zA[16], zB[16];
#pragma unroll
  for (int d = 0; d < 16; ++d) zA[d] = z[((size_t)(c * 16 + d)) * HW + t];
#pragma unroll
  for (int k = 0; k < 8; ++k) {
    if (k < 7) {
#pragma unroll
      for (int d = 0; d < 16; ++d)
        zB[d] = z[((size_t)((k + 1) * 128 + c * 16 + d)) * HW + t];
    }
    const int bi = bidx[k];
    atomicAdd(&s_cnt[bi], 1.0f);  // ds_add_f32, banked
#pragma unroll
    for (int d = 0; d < 16; ++d) atomicAdd(&s_sum[bi * 17 + d], zA[d]);
#pragma unroll
    for (int d = 0; d < 16; ++d) zA[d] = zB[d];
  }
  __syncthreads();

  // new_count + nsum (counts are exact integers -> order-independent)
  const float ncv = 0.99f * ema_count[c * VOCAB + t] + 0.01f * s_cnt[t];
  out[OFF_NCNT + c * VOCAB + t] = ncv;
  float psum = ncv;
#pragma unroll
  for (int off = 32; off; off >>= 1) psum += __shfl_down(psum, off);
  if (lane == 0) s_fred[wv] = psum;
  __syncthreads();
  if (t == 0) {
    float s = 0.f;
#pragma unroll
    for (int i = 0; i < 16; ++i) s += s_fred[i];
    s_n = s;
  }
  __syncthreads();
  const float nsum = s_n;
  const float veps = 0.01024f;  // VOCAB * 1e-5

  // new_weight / new_codebooks: 16 contiguous-coalesced elements per thread
#pragma unroll
  for (int j = 0; j < 16; ++j) {
    const int i = j * 1024 + t;  // element within codebook c
    const int v = i >> 4;
    const int d = i & 15;
    const float nc = 0.99f * ema_count[c * VOCAB + v] + 0.01f * s_cnt[v];
    const float cnt = (nc + 1e-5f) / (nsum + veps) * nsum;
    const size_t gi = (size_t)c * VOCAB * CDIM + i;
    const float nw = 0.99f * ema_weight[gi] + 0.01f * s_sum[v * 17 + d];
    out[OFF_NWT + gi] = nw;
    out[OFF_NCB + gi] = nw / cnt;
  }

  // commitment: block 0 reduces the 1024 f32 partials in f64
  if (c == 0) {
    double ps = (double)ws_commit_arr[t];
#pragma unroll
    for (int off = 32; off; off >>= 1) ps += __shfl_down(ps, off);
    if (lane == 0) s_dred[wv] = ps;
    __syncthreads();
    if (t == 0) {
      double sd = 0.0;
#pragma unroll
      for (int i = 0; i < 16; ++i) sd += s_dred[i];
      out[OFF_COMMIT] = (float)(sd / 1048576.0);
    }
  }
}

extern "C" void kernel_launch(void* const* d_in, const int* in_sizes, int n_in,
                              void* d_out, int out_size, void* d_ws,
                              size_t ws_size, hipStream_t stream) {
  const float* z = (const float*)d_in[0];
  const float* codebooks = (const float*)d_in[1];
  const float* ema_count = (const float*)d_in[2];
  const float* ema_weight = (const float*)d_in[3];
  float* out = (float*)d_out;

  float* ws_commit_arr = (float*)d_ws + WS_CARR_OFF;

  // no memset: commit_arr is fully written by k_assign's 1024 blocks;
  // histograms live in k_statsupd's LDS.

  k_assign<<<dim3(1024), dim3(512), 0, stream>>>(z, codebooks, out,
                                                 ws_commit_arr);
  k_statsupd<<<dim3(8), dim3(1024), 0, stream>>>(z, out, ema_count,
                                                 ema_weight, ws_commit_arr,
                                                 out);
}

// Round 7
// 133.768 us; speedup vs baseline: 2.2434x; 2.2434x over previous
//
#include <hip/hip_runtime.h>

// SimVQuantizer: B=8, D=128 (N_CB=8 x CDIM=16), H=W=32 -> 8192 pixels.
// Outputs (FLOAT32, concatenated flat):
//   quantized  [8,128,32,32]  = 1048576   @ 0
//   indices    [8,8,32,32]    =   65536   @ 1048576
//   commitment scalar         =       1   @ 1114112
//   new_codebooks [8,1024,16] =  131072   @ 1114113
//   new_count  [8,1024]       =    8192   @ 1245185
//   new_weight [8,1024,16]    =  131072   @ 1253377

#define NCB   8
#define VOCAB 1024
#define CDIM  16
#define NPIX  8192   // B*H*W
#define HW    1024   // H*W

#define OFF_QUANT  0
#define OFF_IDX    1048576
#define OFF_COMMIT 1114112
#define OFF_NCB    1114113
#define OFF_NCNT   1245185
#define OFF_NWT    1253377

// workspace layout (floats):
//   counts_p [8][2][1024]      @ 0       (per-(c,half) partial counts)
//   sums_p   [8][16][2][1024]  @ 16384   (per-(c,d,half) partial sums)
//   commit_arr [1024]          @ 278528  (per-assign-block partials)
// No memset: every word is written before it is read.
#define WS_CNTP_OFF 0
#define WS_SUMP_OFF (NCB * 2 * VOCAB)
#define WS_CARR_OFF (NCB * 2 * VOCAB + NCB * CDIM * 2 * VOCAB)

// numpy pairwise_sum (order-preserving 8-accumulator) for n=16:
// r[j] = a[j] + a[j+8];  res = ((r0+r1)+(r2+r3)) + ((r4+r5)+(r6+r7))
__device__ __forceinline__ float npsum16(const float m[16]) {
#pragma clang fp contract(off)
  float r0 = m[0] + m[8];
  float r1 = m[1] + m[9];
  float r2 = m[2] + m[10];
  float r3 = m[3] + m[11];
  float r4 = m[4] + m[12];
  float r5 = m[5] + m[13];
  float r6 = m[6] + m[14];
  float r7 = m[7] + m[15];
  return ((r0 + r1) + (r2 + r3)) + ((r4 + r5) + (r6 + r7));
}

__device__ __forceinline__ float npsum16sq(const float a[16]) {
#pragma clang fp contract(off)
  float m[16];
#pragma unroll
  for (int d = 0; d < 16; ++d) m[d] = a[d] * a[d];
  return npsum16(m);
}

// One entry's distance + argmin step. numpy einsum (optimize=False) npyv
// contig order for n=16, then (z2 - 2*dot) + c2 — bit-identical to v1.
__device__ __forceinline__ void proc_entry(const float zv[16],
                                           const float e[16], float c2v,
                                           float z2, int idx, float& best,
                                           int& bi) {
#pragma clang fp contract(off)
  float m[16];
#pragma unroll
  for (int d = 0; d < 16; ++d) m[d] = zv[d] * e[d];
  float l0 = (m[0] + m[4]) + (m[8] + m[12]);
  float l1 = (m[1] + m[5]) + (m[9] + m[13]);
  float l2 = (m[2] + m[6]) + (m[10] + m[14]);
  float l3 = (m[3] + m[7]) + (m[11] + m[15]);
  const float dot = (l0 + l1) + (l2 + l3);
  const float d2 = (z2 - 2.0f * dot) + c2v;
  const bool lt = d2 < best;  // strict: ascending scan -> first-wins
  best = lt ? d2 : best;
  bi = lt ? idx : bi;
}

// v8: k_assign UNCHANGED from v6/v7 (control: 63.6us, VALUBusy 64%).
// Entries stream via wave-uniform scalar loads; no atomics anywhere.
__global__ __launch_bounds__(512, 4) void k_assign(
    const float* __restrict__ z, const float* __restrict__ cb,
    float* __restrict__ out, float* __restrict__ ws_commit_arr) {
  __shared__ float s_c2[VOCAB];    // 4KB
  __shared__ float s_best[8 * 64]; // 2KB
  __shared__ int s_bi[8 * 64];     // 2KB

  const int c = blockIdx.x >> 7;
  const int pchunk = blockIdx.x & 127;
  const int t = threadIdx.x;
  const int pix = t & 63;
  const int w = t >> 6;
  // provably wave-uniform wave id -> scalar (SGPR) entry addressing below
  const int wu = __builtin_amdgcn_readfirstlane(w);

  const float* cbc = cb + (size_t)c * VOCAB * CDIM;

  // ||cb||^2 for all 1024 entries (np.sum(cb*cb,-1), pairwise 8-acc order)
  for (int v = t; v < VOCAB; v += 512) {
    float e[16];
#pragma unroll
    for (int d = 0; d < 16; ++d) e[d] = cbc[(size_t)v * CDIM + d];
    s_c2[v] = npsum16sq(e);
  }

  const int n = pchunk * 64 + pix;  // pixel id in [0, 8192)
  const int b = n >> 10;            // batch
  const int hw = n & 1023;          // h*W + w

  // zp[n,c,d] = z[b, c*16+d, h, w]; 64-lane coalesced per d
  const float* zbase = z + ((size_t)(b * 128 + c * 16)) * HW + hw;
  float zv[16];
#pragma unroll
  for (int d = 0; d < 16; ++d) zv[d] = zbase[(size_t)d * HW];

  const float z2 = npsum16sq(zv);

  __syncthreads();  // s_c2 ready

  // wave wu scans entries [wu*128, wu*128+128), ascending
  const int vbase = wu * 128;
  const float* ep = cbc + (size_t)vbase * CDIM;  // uniform (SGPR) pointer

  float best = INFINITY;
  int bi = 0;

#pragma unroll 2
  for (int k = 0; k < 128; k += 2) {
    // two entries per body; unroll 2 -> 4 entries of load-ahead slack for
    // the scheduler. All addresses uniform -> scalar loads.
    float ea[16], eb[16];
#pragma unroll
    for (int d = 0; d < 16; ++d) ea[d] = ep[(size_t)k * CDIM + d];
#pragma unroll
    for (int d = 0; d < 16; ++d) eb[d] = ep[(size_t)(k + 1) * CDIM + d];
    const float cv0 = s_c2[vbase + k];
    const float cv1 = s_c2[vbase + k + 1];
    proc_entry(zv, ea, cv0, z2, vbase + k, best, bi);
    proc_entry(zv, eb, cv1, z2, vbase + k + 1, best, bi);
  }

  s_best[w * 64 + pix] = best;
  s_bi[w * 64 + pix] = bi;
  __syncthreads();

  // wave 0: combine the 8 per-wave candidates. Wave slices are disjoint
  // ascending ranges; break float ties by lower index -> np.argmin
  // first-wins exactly.
  if (t < 64) {
    best = s_best[t];
    bi = s_bi[t];
#pragma unroll
    for (int s = 1; s < 8; ++s) {
      const float ob = s_best[s * 64 + t];
      const int oi = s_bi[s * 64 + t];
      const bool take = (ob < best) || (ob == best && oi < bi);
      best = take ? ob : best;
      bi = take ? oi : bi;
    }

    // t<64 => wave 0, pix == t: zv holds THIS pixel's z (bit-identical)
    const float* qe = cbc + (size_t)bi * CDIM;  // winning entry (L2-hot)
    float comm = 0.f;
#pragma unroll
    for (int d = 0; d < 16; ++d) {
      float zq = qe[d];
      float diff, qst;
      {
#pragma clang fp contract(off)
        diff = zv[d] - zq;
        qst = zv[d] + (zq - zv[d]);  // zq_st = zp + (zq - zp), as np computes
      }
      comm += diff * diff;
      out[OFF_QUANT + ((size_t)(b * 128 + c * 16 + d)) * HW + hw] = qst;
    }
    out[OFF_IDX + ((size_t)(b * NCB + c)) * HW + hw] = (float)bi;

    // commitment partial: reduce across wave 0's 64 lanes, ONE plain store
    // per block (no atomics anywhere in this kernel).
#pragma unroll
    for (int off = 32; off; off >>= 1) comm += __shfl_down(comm, off);
    if (t == 0) atomicAdd(ws_commit_arr + blockIdx.x, 0.0f),
        ws_commit_arr[blockIdx.x] = comm;
  }
}

// k_stats v8: 256 blocks = (c, d, half) x 1024 threads. Each block bins
// HALF the pixels (4 batches) for one (c,d) into an LDS histogram, then
// writes a dense partial. vs v6: loads hoisted (one latency exposure, 8
// regs — no spill possible), 2x blocks (both fixes from the v7 post-
// mortem: v7's 8-block/74KB-LDS fusion spilled at VGPR=32 with 1.5%
// occupancy -> 184us). Zero global atomics.
__global__ __launch_bounds__(1024, 4) void k_stats(
    const float* __restrict__ z, const float* __restrict__ outbuf,
    float* __restrict__ ws_counts_p, float* __restrict__ ws_sums_p) {
  __shared__ float s_sum[VOCAB];  // 4KB
  __shared__ float s_cnt[VOCAB];  // 4KB (d==0 blocks only)
  const int c = blockIdx.x >> 5;
  const int d = (blockIdx.x >> 1) & 15;
  const int half = blockIdx.x & 1;
  const int t = threadIdx.x;

  s_sum[t] = 0.f;
  if (d == 0) s_cnt[t] = 0.f;

  // hoist all loads: 4 idx + 4 z, independent -> one latency exposure
  int bidx[4];
  float zval[4];
#pragma unroll
  for (int k = 0; k < 4; ++k) {
    const int bb = half * 4 + k;  // batch
    bidx[k] = (int)outbuf[OFF_IDX + ((size_t)(bb * NCB + c)) * HW + t];
    zval[k] = z[((size_t)(bb * 128 + c * 16 + d)) * HW + t];
  }
  __syncthreads();  // zero-init visible

#pragma unroll
  for (int k = 0; k < 4; ++k) {
    atomicAdd(&s_sum[bidx[k]], zval[k]);  // ds_add_f32, banked
    if (d == 0) atomicAdd(&s_cnt[bidx[k]], 1.0f);
  }
  __syncthreads();

  ws_sums_p[((size_t)((c * CDIM + d) * 2 + half)) * VOCAB + t] = s_sum[t];
  if (d == 0) ws_counts_p[(c * 2 + half) * VOCAB + t] = s_cnt[t];
}

// EMA update + Laplace-smoothed normalization. 64 blocks x 256 threads:
// block = (c, part). Counts are exact integers so partial-sum order is
// exact; sum partials add in fixed (half0+half1) order. Block 0 also
// reduces the 1024 commitment partials in f64.
__global__ __launch_bounds__(256) void k_update(
    const float* __restrict__ ema_count, const float* __restrict__ ema_weight,
    const float* __restrict__ ws_counts_p, const float* __restrict__ ws_sums_p,
    const float* __restrict__ ws_commit_arr, float* __restrict__ out) {
  const int c = blockIdx.x >> 3;
  const int part = blockIdx.x & 7;
  const int t = threadIdx.x;
  __shared__ float s_red[4];
  __shared__ float s_n;
  __shared__ double s_dred[4];

  const float* cp0 = ws_counts_p + (c * 2 + 0) * VOCAB;
  const float* cp1 = ws_counts_p + (c * 2 + 1) * VOCAB;

  float psum = 0.f;
#pragma unroll
  for (int k = 0; k < 4; ++k) {
    const int v = k * 256 + t;
    psum += 0.99f * ema_count[c * VOCAB + v] + 0.01f * (cp0[v] + cp1[v]);
  }
#pragma unroll
  for (int off = 32; off; off >>= 1) psum += __shfl_down(psum, off);
  if ((t & 63) == 0) s_red[t >> 6] = psum;
  __syncthreads();
  if (t == 0) s_n = (s_red[0] + s_red[1]) + (s_red[2] + s_red[3]);
  __syncthreads();
  const float nsum = s_n;
  const float veps = 0.01024f;  // VOCAB * 1e-5

  // new_count: 128 entries per block
  if (t < 128) {
    const int v = part * 128 + t;
    out[OFF_NCNT + c * VOCAB + v] =
        0.99f * ema_count[c * VOCAB + v] + 0.01f * (cp0[v] + cp1[v]);
  }

  // new_weight / new_codebooks: 2048 elements per block, coalesced stores;
  // sum partials read from [c][d][half][v] layout (L2-hot, 1MB total)
#pragma unroll
  for (int k = 0; k < 8; ++k) {
    const int i = part * 2048 + k * 256 + t;  // element within codebook c
    const int v = i >> 4;
    const int d = i & 15;
    const float nc =
        0.99f * ema_count[c * VOCAB + v] + 0.01f * (cp0[v] + cp1[v]);
    const float cnt = (nc + 1e-5f) / (nsum + veps) * nsum;
    const size_t gi = (size_t)c * VOCAB * CDIM + i;
    const float s0 = ws_sums_p[((size_t)((c * CDIM + d) * 2 + 0)) * VOCAB + v];
    const float s1 = ws_sums_p[((size_t)((c * CDIM + d) * 2 + 1)) * VOCAB + v];
    const float nw = 0.99f * ema_weight[gi] + 0.01f * (s0 + s1);
    out[OFF_NWT + gi] = nw;
    out[OFF_NCB + gi] = nw / cnt;
  }

  if (blockIdx.x == 0) {
    double ps = 0.0;
#pragma unroll
    for (int k = 0; k < 4; ++k) ps += (double)ws_commit_arr[k * 256 + t];
#pragma unroll
    for (int off = 32; off; off >>= 1) ps += __shfl_down(ps, off);
    if ((t & 63) == 0) s_dred[t >> 6] = ps;
    __syncthreads();
    if (t == 0)
      out[OFF_COMMIT] =
          (float)(((s_dred[0] + s_dred[1]) + (s_dred[2] + s_dred[3])) /
                  1048576.0);
  }
}

extern "C" void kernel_launch(void* const* d_in, const int* in_sizes, int n_in,
                              void* d_out, int out_size, void* d_ws,
                              size_t ws_size, hipStream_t stream) {
  const float* z = (const float*)d_in[0];
  const float* codebooks = (const float*)d_in[1];
  const float* ema_count = (const float*)d_in[2];
  const float* ema_weight = (const float*)d_in[3];
  float* out = (float*)d_out;

  float* wsf = (float*)d_ws;
  float* ws_counts_p = wsf + WS_CNTP_OFF;
  float* ws_sums_p = wsf + WS_SUMP_OFF;
  float* ws_commit_arr = wsf + WS_CARR_OFF;

  // no memset: all workspace words are written before being read

  k_assign<<<dim3(1024), dim3(512), 0, stream>>>(z, codebooks, out,
                                                 ws_commit_arr);
  k_stats<<<dim3(256), dim3(1024), 0, stream>>>(z, out, ws_counts_p,
                                                ws_sums_p);
  k_update<<<dim3(64), dim3(256), 0, stream>>>(ema_count, ema_weight,
                                               ws_counts_p, ws_sums_p,
                                               ws_commit_arr, out);
}